// Round 5
// baseline (1147.465 us; speedup 1.0000x reference)
//
#include <hip/hip_runtime.h>
#include <cstdint>

typedef _Float16 f16;
typedef __attribute__((ext_vector_type(8))) _Float16 f16x8;
typedef __attribute__((ext_vector_type(4))) _Float16 f16x4;
typedef __attribute__((ext_vector_type(4))) float f32x4;

typedef __attribute__((address_space(1))) void gvoid_t;
typedef __attribute__((address_space(3))) void lvoid_t;

// async global->LDS, 16B per lane. LDS dest wave-uniform base; HW adds lane*16.
__device__ __forceinline__ void async_copy16(void* lds, const void* g) {
  __builtin_amdgcn_global_load_lds((gvoid_t*)(uintptr_t)g, (lvoid_t*)lds, 16, 0, 0);
}

#define BARRIER()   __builtin_amdgcn_s_barrier()
#define SCHEDBAR()  __builtin_amdgcn_sched_barrier(0)
#define VMCNT4()    do { asm volatile("s_waitcnt vmcnt(4)"); SCHEDBAR(); } while (0)
#define VMCNT0()    do { asm volatile("s_waitcnt vmcnt(0)"); SCHEDBAR(); } while (0)

struct TileCtx {
  const f16* Ab; const f16* Bb;
  long brow, bcol; int lda, ldb;
  int srow, scol8, sdst;           // staging geometry
  int wr, wc, l15, lk;             // wave/fragment coords
};

// stage one 256x32 tile half-pair (2 x global_load_lds of 8KB)
__device__ __forceinline__ void stage_half(f16* BUF, const f16* P, long r0, int ld,
                                           int tt, const TileCtx& c) {
  async_copy16(BUF + c.sdst,        P + (r0 + c.srow)       * (long)ld + (long)tt * 32 + c.scol8 * 8);
  async_copy16(BUF + 4096 + c.sdst, P + (r0 + 128 + c.srow) * (long)ld + (long)tt * 32 + c.scol8 * 8);
}

// swizzled ds_read of one 16-row fragment (f16x8 per lane)
__device__ __forceinline__ f16x8 rd_frag(const f16* BUF, int rbase, const TileCtx& c) {
  const int r = rbase + c.l15;
  return *reinterpret_cast<const f16x8*>(&BUF[r * 32 + ((c.lk ^ ((r >> 1) & 3)) * 8)]);
}

// One K-tile, software-pipelined: MFMA consumes frags read LAST tile; this tile
// reads next tile's frags; ONE barrier + counted vmcnt(4) per tile.
// CA/CB: current bufs (afc/bfc already hold m0-3 / n0-3 frags of CA/CB).
// NA/NB: next tile's bufs (prefetch frags). GA/GB: stage targets (tile tt_stage).
__device__ __forceinline__ void tile_body(
    const f16* CA, const f16* NA, const f16* NB,
    f16* GA, f16* GB, bool do_stage, bool do_next, int tt_stage,
    const TileCtx& c, f16x8 (&afc)[4], f16x8 (&bfc)[4], f32x4 (&acc)[8][4])
{
  f16x8 af1[4], afn[4], bfn[4];

  if (do_stage) stage_half(GA, c.Ab, c.brow, c.lda, tt_stage, c);   // A(t+3)
  af1[0] = rd_frag(CA, c.wr * 128 + 64,  c);                        // this tile m4-7
  af1[1] = rd_frag(CA, c.wr * 128 + 80,  c);
  af1[2] = rd_frag(CA, c.wr * 128 + 96,  c);
  af1[3] = rd_frag(CA, c.wr * 128 + 112, c);

  __builtin_amdgcn_s_setprio(1);
#pragma unroll
  for (int m = 0; m < 4; ++m)
#pragma unroll
    for (int n = 0; n < 4; ++n)
      acc[m][n] = __builtin_amdgcn_mfma_f32_16x16x32_f16(afc[m], bfc[n], acc[m][n], 0, 0, 0);
  __builtin_amdgcn_s_setprio(0);

  if (do_stage) stage_half(GB, c.Bb, c.bcol, c.ldb, tt_stage, c);   // B(t+3)
  if (do_next) {                                                    // next tile m0-3 / n0-3
    afn[0] = rd_frag(NA, c.wr * 128 + 0,  c);
    afn[1] = rd_frag(NA, c.wr * 128 + 16, c);
    afn[2] = rd_frag(NA, c.wr * 128 + 32, c);
    afn[3] = rd_frag(NA, c.wr * 128 + 48, c);
    bfn[0] = rd_frag(NB, c.wc * 64 + 0,   c);
    bfn[1] = rd_frag(NB, c.wc * 64 + 16,  c);
    bfn[2] = rd_frag(NB, c.wc * 64 + 32,  c);
    bfn[3] = rd_frag(NB, c.wc * 64 + 48,  c);
  }

  __builtin_amdgcn_s_setprio(1);
#pragma unroll
  for (int m = 0; m < 4; ++m)
#pragma unroll
    for (int n = 0; n < 4; ++n)
      acc[m + 4][n] = __builtin_amdgcn_mfma_f32_16x16x32_f16(af1[m], bfc[n], acc[m + 4][n], 0, 0, 0);
  __builtin_amdgcn_s_setprio(0);

  // drain loads issued two tiles ago (tile t+2's data, read next tile); keep
  // this tile's 4 staging loads (t+3) in flight across the barrier.
  if (do_stage) { VMCNT4(); } else { VMCNT0(); }
  BARRIER();

  if (do_next) {
#pragma unroll
    for (int i = 0; i < 4; ++i) { afc[i] = afn[i]; bfc[i] = bfn[i]; }
  }
}

// 256x256 tile, BK=32, 8 waves (2M x 4N), 4-deep ring of NAMED LDS buffers,
// frag prefetch one tile ahead, 1 barrier/tile.  K % 128 == 0.
template<int OUT_F16>
__global__ __launch_bounds__(512, 2)
void gemm256(const f16* __restrict__ A, int lda, long sA,
             const f16* __restrict__ B, int ldb, long sB,
             void* __restrict__ Cv, int ldc, long sC,
             const float* __restrict__ bias, float scale, int K)
{
  __shared__ f16 SA0[8192]; __shared__ f16 SA1[8192];
  __shared__ f16 SA2[8192]; __shared__ f16 SA3[8192];
  __shared__ f16 SB0[8192]; __shared__ f16 SB1[8192];
  __shared__ f16 SB2[8192]; __shared__ f16 SB3[8192];

  const int tid  = threadIdx.x;
  const int lane = tid & 63;
  const int wave = tid >> 6;        // 0..7
  const int z = blockIdx.z;

  TileCtx c;
  c.Ab = A + (long)z * sA;
  c.Bb = B + (long)z * sB;
  c.brow = (long)blockIdx.y * 256;
  c.bcol = (long)blockIdx.x * 256;
  c.lda = lda; c.ldb = ldb;
  c.srow  = tid >> 2;                      // 0..127
  c.scol8 = (tid & 3) ^ ((tid >> 3) & 3);  // pre-swizzled col block (pairs with rd_frag XOR)
  c.sdst  = wave * 512;                    // wave-uniform elem offset within half
  c.wr = wave >> 2;                        // M half (128 rows)
  c.wc = wave & 3;                         // N quarter (64 cols)
  c.l15 = lane & 15; c.lk = lane >> 4;

  f32x4 acc[8][4] = {};
  const int NT = K >> 5;                   // 64 for K=2048

  // prologue: stage tiles 0,1,2 (12 loads); vmcnt(4): t0,t1 landed, t2 in flight
  stage_half(SA0, c.Ab, c.brow, c.lda, 0, c);
  stage_half(SB0, c.Bb, c.bcol, c.ldb, 0, c);
  stage_half(SA1, c.Ab, c.brow, c.lda, 1, c);
  stage_half(SB1, c.Bb, c.bcol, c.ldb, 1, c);
  stage_half(SA2, c.Ab, c.brow, c.lda, 2, c);
  stage_half(SB2, c.Bb, c.bcol, c.ldb, 2, c);
  VMCNT4();
  BARRIER();

  // pre-read tile 0 fragments (m0-3, n0-3)
  f16x8 afc[4], bfc[4];
  afc[0] = rd_frag(SA0, c.wr * 128 + 0,  c);
  afc[1] = rd_frag(SA0, c.wr * 128 + 16, c);
  afc[2] = rd_frag(SA0, c.wr * 128 + 32, c);
  afc[3] = rd_frag(SA0, c.wr * 128 + 48, c);
  bfc[0] = rd_frag(SB0, c.wc * 64 + 0,   c);
  bfc[1] = rd_frag(SB0, c.wc * 64 + 16,  c);
  bfc[2] = rd_frag(SB0, c.wc * 64 + 32,  c);
  bfc[3] = rd_frag(SB0, c.wc * 64 + 48,  c);

  for (int t4 = 0; t4 < NT; t4 += 4) {
    tile_body(SA0, SA1, SB1, SA3, SB3, t4 + 3 < NT, t4 + 1 < NT, t4 + 3, c, afc, bfc, acc);
    tile_body(SA1, SA2, SB2, SA0, SB0, t4 + 4 < NT, t4 + 2 < NT, t4 + 4, c, afc, bfc, acc);
    tile_body(SA2, SA3, SB3, SA1, SB1, t4 + 5 < NT, t4 + 3 < NT, t4 + 5, c, afc, bfc, acc);
    tile_body(SA3, SA0, SB0, SA2, SB2, t4 + 6 < NT, t4 + 4 < NT, t4 + 6, c, afc, bfc, acc);
  }

  // epilogue: C/D layout col = lane&15, row = (lane>>4)*4 + j
#pragma unroll
  for (int m = 0; m < 8; ++m) {
#pragma unroll
    for (int n = 0; n < 4; ++n) {
      const long col = c.bcol + c.wc * 64 + n * 16 + c.l15;
      const float bv = bias ? bias[col] : 0.0f;
#pragma unroll
      for (int j = 0; j < 4; ++j) {
        const long row = c.brow + c.wr * 128 + m * 16 + c.lk * 4 + j;
        const float v = acc[m][n][j] * scale + bv;
        if (OUT_F16)
          ((f16*)Cv)[(long)z * sC + row * ldc + col] = (f16)v;
        else
          ((float*)Cv)[(long)z * sC + row * ldc + col] = v;
      }
    }
  }
}

__global__ void cast_f32_f16(const float* __restrict__ in, f16* __restrict__ out, long n) {
  long i = ((long)blockIdx.x * blockDim.x + threadIdx.x) * 4;
  const long stride = (long)gridDim.x * blockDim.x * 4;
  for (; i < n; i += stride) {
    const float4 v = *reinterpret_cast<const float4*>(in + i);
    f16x4 h;
    h.x = (f16)v.x; h.y = (f16)v.y; h.z = (f16)v.z; h.w = (f16)v.w;
    *reinterpret_cast<f16x4*>(out + i) = h;
  }
}

// vt[b][h][s] = qkv[b*2048+s][4096+h]   (extract V and transpose, per batch)
__global__ __launch_bounds__(256)
void transpose_v(const f16* __restrict__ qkv, f16* __restrict__ vt) {
  __shared__ f16 t[32][33];
  const int b = blockIdx.z;
  const int s0 = blockIdx.y * 32, h0 = blockIdx.x * 32;
  const int tx = threadIdx.x, ty = threadIdx.y;  // 32 x 8
  const f16* src = qkv + (long)b * 2048 * 6144 + 4096;
  f16* dst = vt + (long)b * 2048 * 2048;
#pragma unroll
  for (int i = 0; i < 4; ++i)
    t[ty + i * 8][tx] = src[(long)(s0 + ty + i * 8) * 6144 + h0 + tx];
  __syncthreads();
#pragma unroll
  for (int i = 0; i < 4; ++i)
    dst[(long)(h0 + ty + i * 8) * 2048 + s0 + tx] = t[tx][ty + i * 8];
}

// one block per row of 2048 f32 scores; writes f16 probs in-place (row stride 4096 f16)
__global__ __launch_bounds__(256)
void softmax_rows(float* __restrict__ scores) {
  const long row = blockIdx.x;
  float* s = scores + row * 2048;
  const int tid = threadIdx.x;
  const int lane = tid & 63;
  const int wave = tid >> 6;

  const float4 a = *reinterpret_cast<const float4*>(s + tid * 8);
  const float4 b = *reinterpret_cast<const float4*>(s + tid * 8 + 4);
  float v[8] = {a.x, a.y, a.z, a.w, b.x, b.y, b.z, b.w};

  float mx = v[0];
#pragma unroll
  for (int j = 1; j < 8; ++j) mx = fmaxf(mx, v[j]);
#pragma unroll
  for (int off = 32; off >= 1; off >>= 1) mx = fmaxf(mx, __shfl_xor(mx, off));
  __shared__ float red[4];
  if (lane == 0) red[wave] = mx;
  __syncthreads();
  mx = fmaxf(fmaxf(red[0], red[1]), fmaxf(red[2], red[3]));

  float sum = 0.f;
#pragma unroll
  for (int j = 0; j < 8; ++j) { v[j] = __expf(v[j] - mx); sum += v[j]; }
#pragma unroll
  for (int off = 32; off >= 1; off >>= 1) sum += __shfl_xor(sum, off);
  __shared__ float red2[4];
  if (lane == 0) red2[wave] = sum;
  __syncthreads();
  const float inv = 1.0f / (red2[0] + red2[1] + red2[2] + red2[3]);

  f16* p = reinterpret_cast<f16*>(scores) + row * 4096 + tid * 8;
  f16x8 h;
#pragma unroll
  for (int j = 0; j < 8; ++j) h[j] = (f16)(v[j] * inv);
  *reinterpret_cast<f16x8*>(p) = h;
}

extern "C" void kernel_launch(void* const* d_in, const int* in_sizes, int n_in,
                              void* d_out, int out_size, void* d_ws, size_t ws_size,
                              hipStream_t stream) {
  const float* x     = (const float*)d_in[0];  // [4,2048,2048]
  const float* w_qkv = (const float*)d_in[1];  // [6144,2048]
  const float* b_qkv = (const float*)d_in[2];  // [6144]
  const float* w_out = (const float*)d_in[3];  // [2048,2048]
  const float* b_out = (const float*)d_in[4];  // [2048]
  float* out = (float*)d_out;                  // [4,2048,2048] f32

  char* ws = (char*)d_ws;
  f16*   Xh    = (f16*)(ws + 0);           //  33.5 MB  [8192][2048]
  f16*   Wqkvh = (f16*)(ws + 33554432L);   //  25.2 MB  [6144][2048]
  f16*   Wouth = (f16*)(ws + 58720256L);   //   8.4 MB  [2048][2048]
  f16*   QKV   = (f16*)(ws + 67108864L);   // 100.7 MB  [8192][6144]
  float* SC    = (float*)(ws + 167772160L);//  67.1 MB  [4][2048][2048] f32 (probs f16 in-place)
  f16*   VT    = (f16*)(ws + 234881024L);  //  33.5 MB  [4][2048][2048]
  f16*   CTX   = Xh;                       // reuse X region after gemm1

  const float inv_sqrt_h = 0.022097086912079608f;  // 1/sqrt(2048)

  cast_f32_f16<<<2048, 256, 0, stream>>>(x,     Xh,    16777216L);
  cast_f32_f16<<<2048, 256, 0, stream>>>(w_qkv, Wqkvh, 12582912L);
  cast_f32_f16<<<1024, 256, 0, stream>>>(w_out, Wouth, 4194304L);

  // qkv = x @ w_qkv^T + b_qkv   [8192 x 6144]
  gemm256<1><<<dim3(24, 32, 1), 512, 0, stream>>>(
      Xh, 2048, 0, Wqkvh, 2048, 0, QKV, 6144, 0, b_qkv, 1.0f, 2048);

  // scores = Q @ K^T / sqrt(H)  per batch  [2048 x 2048] f32
  gemm256<0><<<dim3(8, 8, 4), 512, 0, stream>>>(
      QKV, 6144, 2048L * 6144, QKV + 2048, 6144, 2048L * 6144,
      SC, 2048, 2048L * 2048, nullptr, inv_sqrt_h, 2048);

  transpose_v<<<dim3(64, 64, 4), dim3(32, 8), 0, stream>>>(QKV, VT);

  softmax_rows<<<8192, 256, 0, stream>>>(SC);

  // context = P @ V  per batch (probs f16 in-place in SC, row stride 4096)
  gemm256<1><<<dim3(8, 8, 4), 512, 0, stream>>>(
      (const f16*)SC, 4096, 2048L * 4096, VT, 2048, 2048L * 2048,
      CTX, 2048, 2048L * 2048, nullptr, 1.0f, 2048);

  // out = context @ w_out^T + b_out   [8192 x 2048] f32
  gemm256<0><<<dim3(8, 32, 1), 512, 0, stream>>>(
      CTX, 2048, 0, Wouth, 2048, 0, out, 2048, 0, b_out, 1.0f, 2048);
}

// Round 6
// 544.813 us; speedup vs baseline: 2.1062x; 2.1062x over previous
//
#include <hip/hip_runtime.h>
#include <cstdint>

typedef _Float16 f16;
typedef __attribute__((ext_vector_type(8))) _Float16 f16x8;
typedef __attribute__((ext_vector_type(4))) _Float16 f16x4;
typedef __attribute__((ext_vector_type(4))) float f32x4;

typedef __attribute__((address_space(1))) void gvoid_t;
typedef __attribute__((address_space(3))) void lvoid_t;

// async global->LDS, 16B per lane. LDS dest wave-uniform base; HW adds lane*16.
__device__ __forceinline__ void async_copy16(void* lds, const void* g) {
  __builtin_amdgcn_global_load_lds((gvoid_t*)(uintptr_t)g, (lvoid_t*)lds, 16, 0, 0);
}

#define BARRIER()   __builtin_amdgcn_s_barrier()
#define SCHEDBAR()  __builtin_amdgcn_sched_barrier(0)
// counted waits, fenced on BOTH sides so no VMEM op migrates across the count
#define VMCNT4()    do { SCHEDBAR(); asm volatile("s_waitcnt vmcnt(4)"); SCHEDBAR(); } while (0)
#define VMCNT0()    do { SCHEDBAR(); asm volatile("s_waitcnt vmcnt(0)"); SCHEDBAR(); } while (0)

struct TileCtx {
  const f16* Ab; const f16* Bb;
  long brow, bcol; int lda, ldb;
  int srow, scol8, sdst;           // staging geometry
  int wr, wc, l15, lk;             // wave/fragment coords
};

// stage one 256x32 tile half-pair (2 x global_load_lds of 8KB)
__device__ __forceinline__ void stage_half(f16* BUF, const f16* P, long r0, int ld,
                                           int tt, const TileCtx& c) {
  async_copy16(BUF + c.sdst,        P + (r0 + c.srow)       * (long)ld + (long)tt * 32 + c.scol8 * 8);
  async_copy16(BUF + 4096 + c.sdst, P + (r0 + 128 + c.srow) * (long)ld + (long)tt * 32 + c.scol8 * 8);
}

// swizzled ds_read of one 16-row fragment (f16x8 per lane)
__device__ __forceinline__ f16x8 rd_frag(const f16* BUF, int rbase, const TileCtx& c) {
  const int r = rbase + c.l15;
  return *reinterpret_cast<const f16x8*>(&BUF[r * 32 + ((c.lk ^ ((r >> 1) & 3)) * 8)]);
}

// One K-tile: ONE barrier + counted vmcnt. Read-buffer is immutable within the
// tile (staging targets a different named buffer), so no intra-tile barriers.
// Frags are NOT carried across tiles (unified VGPR+AGPR budget is 256/lane with
// acc taking 128 AGPR — round-5 spill lesson).
__device__ __forceinline__ void tile_step(const f16* CA, const f16* CB,
                                          f16* NA, f16* NB,
                                          int tc, int NT, const TileCtx& c,
                                          f32x4 (&acc)[8][4]) {
  const bool st = (tc + 2) < NT;
  f16x8 af[8], bf[4];

  if (st) stage_half(NA, c.Ab, c.brow, c.lda, tc + 2, c);   // A(t+2)
  af[0] = rd_frag(CA, c.wr * 128 + 0,   c);
  af[1] = rd_frag(CA, c.wr * 128 + 16,  c);
  af[2] = rd_frag(CA, c.wr * 128 + 32,  c);
  af[3] = rd_frag(CA, c.wr * 128 + 48,  c);
  bf[0] = rd_frag(CB, c.wc * 64 + 0,    c);
  bf[1] = rd_frag(CB, c.wc * 64 + 16,   c);
  bf[2] = rd_frag(CB, c.wc * 64 + 32,   c);
  bf[3] = rd_frag(CB, c.wc * 64 + 48,   c);
  if (st) stage_half(NB, c.Bb, c.bcol, c.ldb, tc + 2, c);   // B(t+2)
  af[4] = rd_frag(CA, c.wr * 128 + 64,  c);
  af[5] = rd_frag(CA, c.wr * 128 + 80,  c);
  af[6] = rd_frag(CA, c.wr * 128 + 96,  c);
  af[7] = rd_frag(CA, c.wr * 128 + 112, c);

  __builtin_amdgcn_s_setprio(1);
#pragma unroll
  for (int m = 0; m < 8; ++m)
#pragma unroll
    for (int n = 0; n < 4; ++n)
      acc[m][n] = __builtin_amdgcn_mfma_f32_16x16x32_f16(af[m], bf[n], acc[m][n], 0, 0, 0);
  __builtin_amdgcn_s_setprio(0);

  // drain tile t+1's 4 loads (oldest outstanding); keep t+2's 4 in flight
  if (st) { VMCNT4(); } else { VMCNT0(); }
  BARRIER();
}

// 256x256 tile, BK=32, 8 waves (2M x 4N), 4-deep ring of NAMED LDS buffers
// (distinct objects => no alias-forced vmcnt(0) before ds_reads). K % 128 == 0.
template<int OUT_F16>
__global__ __launch_bounds__(512, 2)
void gemm256(const f16* __restrict__ A, int lda, long sA,
             const f16* __restrict__ B, int ldb, long sB,
             void* __restrict__ Cv, int ldc, long sC,
             const float* __restrict__ bias, float scale, int K)
{
  __shared__ f16 SA0[8192]; __shared__ f16 SA1[8192];
  __shared__ f16 SA2[8192]; __shared__ f16 SA3[8192];
  __shared__ f16 SB0[8192]; __shared__ f16 SB1[8192];
  __shared__ f16 SB2[8192]; __shared__ f16 SB3[8192];

  const int tid  = threadIdx.x;
  const int lane = tid & 63;
  const int wave = tid >> 6;        // 0..7
  const int z = blockIdx.z;

  TileCtx c;
  c.Ab = A + (long)z * sA;
  c.Bb = B + (long)z * sB;
  c.brow = (long)blockIdx.y * 256;
  c.bcol = (long)blockIdx.x * 256;
  c.lda = lda; c.ldb = ldb;
  c.srow  = tid >> 2;                      // 0..127
  c.scol8 = (tid & 3) ^ ((tid >> 3) & 3);  // pre-swizzled col block (pairs with rd_frag XOR)
  c.sdst  = wave * 512;                    // wave-uniform elem offset within half
  c.wr = wave >> 2;                        // M half (128 rows)
  c.wc = wave & 3;                         // N quarter (64 cols)
  c.l15 = lane & 15; c.lk = lane >> 4;

  f32x4 acc[8][4] = {};
  const int NT = K >> 5;                   // 64 for K=2048

  // prologue: stage tiles 0,1 (8 loads); vmcnt(4): t0 landed, t1 in flight
  stage_half(SA0, c.Ab, c.brow, c.lda, 0, c);
  stage_half(SB0, c.Bb, c.bcol, c.ldb, 0, c);
  stage_half(SA1, c.Ab, c.brow, c.lda, 1, c);
  stage_half(SB1, c.Bb, c.bcol, c.ldb, 1, c);
  VMCNT4();
  BARRIER();

  for (int t4 = 0; t4 < NT; t4 += 4) {
    tile_step(SA0, SB0, SA2, SB2, t4 + 0, NT, c, acc);
    tile_step(SA1, SB1, SA3, SB3, t4 + 1, NT, c, acc);
    tile_step(SA2, SB2, SA0, SB0, t4 + 2, NT, c, acc);
    tile_step(SA3, SB3, SA1, SB1, t4 + 3, NT, c, acc);
  }

  // epilogue: C/D layout col = lane&15, row = (lane>>4)*4 + j
#pragma unroll
  for (int m = 0; m < 8; ++m) {
#pragma unroll
    for (int n = 0; n < 4; ++n) {
      const long col = c.bcol + c.wc * 64 + n * 16 + c.l15;
      const float bv = bias ? bias[col] : 0.0f;
#pragma unroll
      for (int j = 0; j < 4; ++j) {
        const long row = c.brow + c.wr * 128 + m * 16 + c.lk * 4 + j;
        const float v = acc[m][n][j] * scale + bv;
        if (OUT_F16)
          ((f16*)Cv)[(long)z * sC + row * ldc + col] = (f16)v;
        else
          ((float*)Cv)[(long)z * sC + row * ldc + col] = v;
      }
    }
  }
}

__global__ void cast_f32_f16(const float* __restrict__ in, f16* __restrict__ out, long n) {
  long i = ((long)blockIdx.x * blockDim.x + threadIdx.x) * 4;
  const long stride = (long)gridDim.x * blockDim.x * 4;
  for (; i < n; i += stride) {
    const float4 v = *reinterpret_cast<const float4*>(in + i);
    f16x4 h;
    h.x = (f16)v.x; h.y = (f16)v.y; h.z = (f16)v.z; h.w = (f16)v.w;
    *reinterpret_cast<f16x4*>(out + i) = h;
  }
}

// vt[b][h][s] = qkv[b*2048+s][4096+h]   (extract V and transpose, per batch)
__global__ __launch_bounds__(256)
void transpose_v(const f16* __restrict__ qkv, f16* __restrict__ vt) {
  __shared__ f16 t[32][33];
  const int b = blockIdx.z;
  const int s0 = blockIdx.y * 32, h0 = blockIdx.x * 32;
  const int tx = threadIdx.x, ty = threadIdx.y;  // 32 x 8
  const f16* src = qkv + (long)b * 2048 * 6144 + 4096;
  f16* dst = vt + (long)b * 2048 * 2048;
#pragma unroll
  for (int i = 0; i < 4; ++i)
    t[ty + i * 8][tx] = src[(long)(s0 + ty + i * 8) * 6144 + h0 + tx];
  __syncthreads();
#pragma unroll
  for (int i = 0; i < 4; ++i)
    dst[(long)(h0 + ty + i * 8) * 2048 + s0 + tx] = t[tx][ty + i * 8];
}

// one block per row of 2048 f32 scores; writes f16 probs in-place (row stride 4096 f16)
__global__ __launch_bounds__(256)
void softmax_rows(float* __restrict__ scores) {
  const long row = blockIdx.x;
  float* s = scores + row * 2048;
  const int tid = threadIdx.x;
  const int lane = tid & 63;
  const int wave = tid >> 6;

  const float4 a = *reinterpret_cast<const float4*>(s + tid * 8);
  const float4 b = *reinterpret_cast<const float4*>(s + tid * 8 + 4);
  float v[8] = {a.x, a.y, a.z, a.w, b.x, b.y, b.z, b.w};

  float mx = v[0];
#pragma unroll
  for (int j = 1; j < 8; ++j) mx = fmaxf(mx, v[j]);
#pragma unroll
  for (int off = 32; off >= 1; off >>= 1) mx = fmaxf(mx, __shfl_xor(mx, off));
  __shared__ float red[4];
  if (lane == 0) red[wave] = mx;
  __syncthreads();
  mx = fmaxf(fmaxf(red[0], red[1]), fmaxf(red[2], red[3]));

  float sum = 0.f;
#pragma unroll
  for (int j = 0; j < 8; ++j) { v[j] = __expf(v[j] - mx); sum += v[j]; }
#pragma unroll
  for (int off = 32; off >= 1; off >>= 1) sum += __shfl_xor(sum, off);
  __shared__ float red2[4];
  if (lane == 0) red2[wave] = sum;
  __syncthreads();
  const float inv = 1.0f / (red2[0] + red2[1] + red2[2] + red2[3]);

  f16* p = reinterpret_cast<f16*>(scores) + row * 4096 + tid * 8;
  f16x8 h;
#pragma unroll
  for (int j = 0; j < 8; ++j) h[j] = (f16)(v[j] * inv);
  *reinterpret_cast<f16x8*>(p) = h;
}

extern "C" void kernel_launch(void* const* d_in, const int* in_sizes, int n_in,
                              void* d_out, int out_size, void* d_ws, size_t ws_size,
                              hipStream_t stream) {
  const float* x     = (const float*)d_in[0];  // [4,2048,2048]
  const float* w_qkv = (const float*)d_in[1];  // [6144,2048]
  const float* b_qkv = (const float*)d_in[2];  // [6144]
  const float* w_out = (const float*)d_in[3];  // [2048,2048]
  const float* b_out = (const float*)d_in[4];  // [2048]
  float* out = (float*)d_out;                  // [4,2048,2048] f32

  char* ws = (char*)d_ws;
  f16*   Xh    = (f16*)(ws + 0);           //  33.5 MB  [8192][2048]
  f16*   Wqkvh = (f16*)(ws + 33554432L);   //  25.2 MB  [6144][2048]
  f16*   Wouth = (f16*)(ws + 58720256L);   //   8.4 MB  [2048][2048]
  f16*   QKV   = (f16*)(ws + 67108864L);   // 100.7 MB  [8192][6144]
  float* SC    = (float*)(ws + 167772160L);//  67.1 MB  [4][2048][2048] f32 (probs f16 in-place)
  f16*   VT    = (f16*)(ws + 234881024L);  //  33.5 MB  [4][2048][2048]
  f16*   CTX   = Xh;                       // reuse X region after gemm1

  const float inv_sqrt_h = 0.022097086912079608f;  // 1/sqrt(2048)

  cast_f32_f16<<<2048, 256, 0, stream>>>(x,     Xh,    16777216L);
  cast_f32_f16<<<2048, 256, 0, stream>>>(w_qkv, Wqkvh, 12582912L);
  cast_f32_f16<<<1024, 256, 0, stream>>>(w_out, Wouth, 4194304L);

  // qkv = x @ w_qkv^T + b_qkv   [8192 x 6144]
  gemm256<1><<<dim3(24, 32, 1), 512, 0, stream>>>(
      Xh, 2048, 0, Wqkvh, 2048, 0, QKV, 6144, 0, b_qkv, 1.0f, 2048);

  // scores = Q @ K^T / sqrt(H)  per batch  [2048 x 2048] f32
  gemm256<0><<<dim3(8, 8, 4), 512, 0, stream>>>(
      QKV, 6144, 2048L * 6144, QKV + 2048, 6144, 2048L * 6144,
      SC, 2048, 2048L * 2048, nullptr, inv_sqrt_h, 2048);

  transpose_v<<<dim3(64, 64, 4), dim3(32, 8), 0, stream>>>(QKV, VT);

  softmax_rows<<<8192, 256, 0, stream>>>(SC);

  // context = P @ V  per batch (probs f16 in-place in SC, row stride 4096)
  gemm256<1><<<dim3(8, 8, 4), 512, 0, stream>>>(
      (const f16*)SC, 4096, 2048L * 4096, VT, 2048, 2048L * 2048,
      CTX, 2048, 2048L * 2048, nullptr, 1.0f, 2048);

  // out = context @ w_out^T + b_out   [8192 x 2048] f32
  gemm256<0><<<dim3(8, 32, 1), 512, 0, stream>>>(
      CTX, 2048, 0, Wouth, 2048, 0, out, 2048, 0, b_out, 1.0f, 2048);
}

// Round 7
// 478.691 us; speedup vs baseline: 2.3971x; 1.1381x over previous
//
#include <hip/hip_runtime.h>
#include <cstdint>

typedef _Float16 f16;
typedef __attribute__((ext_vector_type(8))) _Float16 f16x8;
typedef __attribute__((ext_vector_type(4))) _Float16 f16x4;
typedef __attribute__((ext_vector_type(4))) float f32x4;

typedef __attribute__((address_space(1))) void gvoid_t;
typedef __attribute__((address_space(3))) void lvoid_t;

// async global->LDS, 16B per lane. LDS dest wave-uniform base; HW adds lane*16.
__device__ __forceinline__ void async_copy16(void* lds, const void* g) {
  __builtin_amdgcn_global_load_lds((gvoid_t*)(uintptr_t)g, (lvoid_t*)lds, 16, 0, 0);
}

#define BARRIER()   __builtin_amdgcn_s_barrier()
#define SCHEDBAR()  __builtin_amdgcn_sched_barrier(0)
#define LGKM0()     do { asm volatile("s_waitcnt lgkmcnt(0)" ::: "memory"); SCHEDBAR(); } while (0)
#define VMCNT(n)    do { SCHEDBAR(); asm volatile("s_waitcnt vmcnt(" #n ")"); SCHEDBAR(); } while (0)

#define MFMA16(a, b, c) __builtin_amdgcn_mfma_f32_16x16x32_f16((a), (b), (c), 0, 0, 0)

// 256x256 tile, BK=64, 8 waves (2M x 4N), 8-phase m201-style schedule.
// LDS: 8 named 16KB halves (2 K-tile dbuf x {A,B} x {half a,b}) = 128 KB.
// C[z][m][n] = scale * sum_k A[z][m][k]*B[z][n][k] + bias[n].  K % 128 == 0.
template<int OUT_F16>
__global__ __launch_bounds__(512, 2)
void gemm256(const f16* __restrict__ A, int lda, long sA,
             const f16* __restrict__ B, int ldb, long sB,
             void* __restrict__ Cv, int ldc, long sC,
             const float* __restrict__ bias, float scale, int K)
{
  __shared__ f16 AH0a[8192]; __shared__ f16 AH0b[8192];
  __shared__ f16 AH1a[8192]; __shared__ f16 AH1b[8192];
  __shared__ f16 BH0a[8192]; __shared__ f16 BH0b[8192];
  __shared__ f16 BH1a[8192]; __shared__ f16 BH1b[8192];

  const int tid = threadIdx.x, lane = tid & 63, wave = tid >> 6;
  const int wr = wave >> 2, wc = wave & 3;       // wave -> (M half, N quarter)
  const int l15 = lane & 15, lk = lane >> 4;

  // XCD-aware bijective swizzle of the flattened x-y grid (z untouched)
  int lin = blockIdx.y * gridDim.x + blockIdx.x;
  const int nxy = gridDim.x * gridDim.y;
  if ((nxy & 7) == 0) lin = (lin & 7) * (nxy >> 3) + (lin >> 3);
  const int bx = lin % gridDim.x, by = lin / gridDim.x;

  const long brow = (long)by * 256, bcol = (long)bx * 256;
  const int z = blockIdx.z;
  const f16* Ab = A + (long)z * sA;
  const f16* Bb = B + (long)z * sB;

  // staging: slot=tid covers (row=tid>>3 [+64 for 2nd instr], col8=tid&7) of a
  // 128x64 half; global col-block pre-swizzled gc8 = (tid&7)^(row&7) so that
  // the ds_read side applies the same XOR (both-sides-or-neither, rule 21).
  const int r0  = tid >> 3;                  // 0..63
  const int gc8 = (tid & 7) ^ (r0 & 7);      // (r0+64)&7 == r0&7
  const int sdst = wave * 512;               // wave-uniform elem offset

  const f16* gAa = Ab + (brow + r0) * (long)lda + gc8 * 8;
  const f16* gAb = gAa + 128L * lda;
  const f16* gBa = Bb + (bcol + r0) * (long)ldb + gc8 * 8;
  const f16* gBb = gBa + 128L * ldb;

#define STG(BUF, G, LD, KOFF) { \
    async_copy16(BUF + sdst,        (G) + (KOFF)); \
    async_copy16(BUF + 4096 + sdst, (G) + 64L * (LD) + (KOFF)); }

  // per-wave source halves
  const f16* myA0 = wr ? AH0b : AH0a;
  const f16* myA1 = wr ? AH1b : AH1a;
  const f16* myB0 = (wc & 2) ? BH0b : BH0a;
  const f16* myB1 = (wc & 2) ? BH1b : BH1a;

  // frag read addressing: lr = m16 + l15 (m16 mult of 16 => lr&7 == l15&7)
  const int x8   = l15 & 7;
  const int cb0  = (lk ^ x8) * 8;            // kk=0 col bytes/2
  const int cb1  = ((4 | lk) ^ x8) * 8;      // kk=1
  const int lbA  = l15 * 64;
  const int lbB  = ((wc & 1) * 64 + l15) * 64;

#define RDA4(SRC, MP) { \
    af[0] = *(const f16x8*)&(SRC)[lbA + (2*(MP))   * 1024 + cb0]; \
    af[1] = *(const f16x8*)&(SRC)[lbA + (2*(MP))   * 1024 + cb1]; \
    af[2] = *(const f16x8*)&(SRC)[lbA + (2*(MP)+1) * 1024 + cb0]; \
    af[3] = *(const f16x8*)&(SRC)[lbA + (2*(MP)+1) * 1024 + cb1]; }

#define RDB8(SRC) { \
    bf[0][0] = *(const f16x8*)&(SRC)[lbB + 0 * 1024 + cb0]; \
    bf[1][0] = *(const f16x8*)&(SRC)[lbB + 0 * 1024 + cb1]; \
    bf[0][1] = *(const f16x8*)&(SRC)[lbB + 1 * 1024 + cb0]; \
    bf[1][1] = *(const f16x8*)&(SRC)[lbB + 1 * 1024 + cb1]; \
    bf[0][2] = *(const f16x8*)&(SRC)[lbB + 2 * 1024 + cb0]; \
    bf[1][2] = *(const f16x8*)&(SRC)[lbB + 2 * 1024 + cb1]; \
    bf[0][3] = *(const f16x8*)&(SRC)[lbB + 3 * 1024 + cb0]; \
    bf[1][3] = *(const f16x8*)&(SRC)[lbB + 3 * 1024 + cb1]; }

#define CLUSTER(MP) { \
    __builtin_amdgcn_s_setprio(1); \
    _Pragma("unroll") \
    for (int n = 0; n < 4; ++n) { \
      f32x4 t = MFMA16(af[0], bf[0][n], acc[2*(MP)][n]); \
      acc[2*(MP)][n] = MFMA16(af[1], bf[1][n], t); \
    } \
    _Pragma("unroll") \
    for (int n = 0; n < 4; ++n) { \
      f32x4 t = MFMA16(af[2], bf[0][n], acc[2*(MP)+1][n]); \
      acc[2*(MP)+1][n] = MFMA16(af[3], bf[1][n], t); \
    } \
    __builtin_amdgcn_s_setprio(0); }

  f32x4 acc[8][4] = {};
  f16x8 af[4], bf[2][4];
  const int NIT = K >> 7;                    // 16 for K=2048... (K/128)

  // prologue: T0 (B halves then A halves), T1's B halves; all but BH1 landed.
  STG(BH0a, gBa, ldb, 0);  STG(BH0b, gBb, ldb, 0);
  STG(AH0a, gAa, lda, 0);  STG(AH0b, gAb, lda, 0);
  STG(BH1a, gBa, ldb, 64); STG(BH1b, gBb, ldb, 64);
  VMCNT(4);
  BARRIER();

  for (int it = 0; it < NIT; ++it) {
    const long k1 = 128L * it + 64;          // T+1 k-offset
    const long k2 = k1 + 64, k3 = k1 + 128;  // T+2, T+3
    const bool st = (it + 1 < NIT);

    // ---- K-tile T (buf0): phases 0-3 ----
    RDA4(myA0, 0); RDB8(myB0);
    STG(AH1a, gAa, lda, k1);                 // T+1 A half-a (read from phase 4)
    BARRIER(); LGKM0(); CLUSTER(0); BARRIER();

    RDA4(myA0, 1);
    STG(AH1b, gAb, lda, k1);
    BARRIER(); LGKM0(); CLUSTER(1); BARRIER();

    RDA4(myA0, 2);
    if (st) STG(BH0a, gBa, ldb, k2);         // T+2 B (BH0 dead after phase 0)
    BARRIER(); LGKM0(); CLUSTER(2); BARRIER();

    RDA4(myA0, 3);
    if (st) STG(BH0b, gBb, ldb, k2);
    BARRIER(); LGKM0(); CLUSTER(3);
    if (st) { VMCNT(4); } else { VMCNT(0); } // V1: AH1 + prev BH1 landed
    BARRIER();

    // ---- K-tile T+1 (buf1): phases 4-7 ----
    RDA4(myA1, 0); RDB8(myB1);
    if (st) STG(AH0a, gAa, lda, k2);         // T+2 A (AH0 dead after phase 3)
    BARRIER(); LGKM0(); CLUSTER(0); BARRIER();

    RDA4(myA1, 1);
    if (st) STG(AH0b, gAb, lda, k2);
    BARRIER(); LGKM0(); CLUSTER(1); BARRIER();

    RDA4(myA1, 2);
    if (st) STG(BH1a, gBa, ldb, k3);         // T+3 B (BH1 dead after phase 4)
    BARRIER(); LGKM0(); CLUSTER(2); BARRIER();

    RDA4(myA1, 3);
    if (st) STG(BH1b, gBb, ldb, k3);
    BARRIER(); LGKM0(); CLUSTER(3);
    if (st) VMCNT(4);                        // V2: BH0 + AH0 landed
    BARRIER();
  }

  // epilogue: C/D layout col = lane&15, row = (lane>>4)*4 + j
#pragma unroll
  for (int m = 0; m < 8; ++m) {
#pragma unroll
    for (int n = 0; n < 4; ++n) {
      const long col = bcol + wc * 64 + n * 16 + l15;
      const float bv = bias ? bias[col] : 0.0f;
#pragma unroll
      for (int j = 0; j < 4; ++j) {
        const long row = brow + wr * 128 + m * 16 + lk * 4 + j;
        const float v = acc[m][n][j] * scale + bv;
        if (OUT_F16)
          ((f16*)Cv)[(long)z * sC + row * ldc + col] = (f16)v;
        else
          ((float*)Cv)[(long)z * sC + row * ldc + col] = v;
      }
    }
  }
#undef STG
#undef RDA4
#undef RDB8
#undef CLUSTER
}

__global__ void cast_f32_f16(const float* __restrict__ in, f16* __restrict__ out, long n) {
  long i = ((long)blockIdx.x * blockDim.x + threadIdx.x) * 4;
  const long stride = (long)gridDim.x * blockDim.x * 4;
  for (; i < n; i += stride) {
    const float4 v = *reinterpret_cast<const float4*>(in + i);
    f16x4 h;
    h.x = (f16)v.x; h.y = (f16)v.y; h.z = (f16)v.z; h.w = (f16)v.w;
    *reinterpret_cast<f16x4*>(out + i) = h;
  }
}

// vt[b][h][s] = qkv[b*2048+s][4096+h]   (extract V and transpose, per batch)
__global__ __launch_bounds__(256)
void transpose_v(const f16* __restrict__ qkv, f16* __restrict__ vt) {
  __shared__ f16 t[32][33];
  const int b = blockIdx.z;
  const int s0 = blockIdx.y * 32, h0 = blockIdx.x * 32;
  const int tx = threadIdx.x, ty = threadIdx.y;  // 32 x 8
  const f16* src = qkv + (long)b * 2048 * 6144 + 4096;
  f16* dst = vt + (long)b * 2048 * 2048;
#pragma unroll
  for (int i = 0; i < 4; ++i)
    t[ty + i * 8][tx] = src[(long)(s0 + ty + i * 8) * 6144 + h0 + tx];
  __syncthreads();
#pragma unroll
  for (int i = 0; i < 4; ++i)
    dst[(long)(h0 + ty + i * 8) * 2048 + s0 + tx] = t[tx][ty + i * 8];
}

// one block per row of 2048 f32 scores; writes f16 probs in-place (row stride 4096 f16)
__global__ __launch_bounds__(256)
void softmax_rows(float* __restrict__ scores) {
  const long row = blockIdx.x;
  float* s = scores + row * 2048;
  const int tid = threadIdx.x;
  const int lane = tid & 63;
  const int wave = tid >> 6;

  const float4 a = *reinterpret_cast<const float4*>(s + tid * 8);
  const float4 b = *reinterpret_cast<const float4*>(s + tid * 8 + 4);
  float v[8] = {a.x, a.y, a.z, a.w, b.x, b.y, b.z, b.w};

  float mx = v[0];
#pragma unroll
  for (int j = 1; j < 8; ++j) mx = fmaxf(mx, v[j]);
#pragma unroll
  for (int off = 32; off >= 1; off >>= 1) mx = fmaxf(mx, __shfl_xor(mx, off));
  __shared__ float red[4];
  if (lane == 0) red[wave] = mx;
  __syncthreads();
  mx = fmaxf(fmaxf(red[0], red[1]), fmaxf(red[2], red[3]));

  float sum = 0.f;
#pragma unroll
  for (int j = 0; j < 8; ++j) { v[j] = __expf(v[j] - mx); sum += v[j]; }
#pragma unroll
  for (int off = 32; off >= 1; off >>= 1) sum += __shfl_xor(sum, off);
  __shared__ float red2[4];
  if (lane == 0) red2[wave] = sum;
  __syncthreads();
  const float inv = 1.0f / (red2[0] + red2[1] + red2[2] + red2[3]);

  f16* p = reinterpret_cast<f16*>(scores) + row * 4096 + tid * 8;
  f16x8 h;
#pragma unroll
  for (int j = 0; j < 8; ++j) h[j] = (f16)(v[j] * inv);
  *reinterpret_cast<f16x8*>(p) = h;
}

extern "C" void kernel_launch(void* const* d_in, const int* in_sizes, int n_in,
                              void* d_out, int out_size, void* d_ws, size_t ws_size,
                              hipStream_t stream) {
  const float* x     = (const float*)d_in[0];  // [4,2048,2048]
  const float* w_qkv = (const float*)d_in[1];  // [6144,2048]
  const float* b_qkv = (const float*)d_in[2];  // [6144]
  const float* w_out = (const float*)d_in[3];  // [2048,2048]
  const float* b_out = (const float*)d_in[4];  // [2048]
  float* out = (float*)d_out;                  // [4,2048,2048] f32

  char* ws = (char*)d_ws;
  f16*   Xh    = (f16*)(ws + 0);           //  33.5 MB  [8192][2048]
  f16*   Wqkvh = (f16*)(ws + 33554432L);   //  25.2 MB  [6144][2048]
  f16*   Wouth = (f16*)(ws + 58720256L);   //   8.4 MB  [2048][2048]
  f16*   QKV   = (f16*)(ws + 67108864L);   // 100.7 MB  [8192][6144]
  float* SC    = (float*)(ws + 167772160L);//  67.1 MB  [4][2048][2048] f32 (probs f16 in-place)
  f16*   VT    = (f16*)(ws + 234881024L);  //  33.5 MB  [4][2048][2048]
  f16*   CTX   = Xh;                       // reuse X region after gemm1

  const float inv_sqrt_h = 0.022097086912079608f;  // 1/sqrt(2048)

  cast_f32_f16<<<2048, 256, 0, stream>>>(x,     Xh,    16777216L);
  cast_f32_f16<<<2048, 256, 0, stream>>>(w_qkv, Wqkvh, 12582912L);
  cast_f32_f16<<<1024, 256, 0, stream>>>(w_out, Wouth, 4194304L);

  // qkv = x @ w_qkv^T + b_qkv   [8192 x 6144]
  gemm256<1><<<dim3(24, 32, 1), 512, 0, stream>>>(
      Xh, 2048, 0, Wqkvh, 2048, 0, QKV, 6144, 0, b_qkv, 1.0f, 2048);

  // scores = Q @ K^T / sqrt(H)  per batch  [2048 x 2048] f32
  gemm256<0><<<dim3(8, 8, 4), 512, 0, stream>>>(
      QKV, 6144, 2048L * 6144, QKV + 2048, 6144, 2048L * 6144,
      SC, 2048, 2048L * 2048, nullptr, inv_sqrt_h, 2048);

  transpose_v<<<dim3(64, 64, 4), dim3(32, 8), 0, stream>>>(QKV, VT);

  softmax_rows<<<8192, 256, 0, stream>>>(SC);

  // context = P @ V  per batch (probs f16 in-place in SC, row stride 4096)
  gemm256<1><<<dim3(8, 8, 4), 512, 0, stream>>>(
      (const f16*)SC, 4096, 2048L * 4096, VT, 2048, 2048L * 2048,
      CTX, 2048, 2048L * 2048, nullptr, 1.0f, 2048);

  // out = context @ w_out^T + b_out   [8192 x 2048] f32
  gemm256<0><<<dim3(8, 32, 1), 512, 0, stream>>>(
      CTX, 2048, 0, Wouth, 2048, 0, out, 2048, 0, b_out, 1.0f, 2048);
}

// Round 8
// 461.054 us; speedup vs baseline: 2.4888x; 1.0383x over previous
//
#include <hip/hip_runtime.h>
#include <cstdint>

typedef _Float16 f16;
typedef __attribute__((ext_vector_type(8))) _Float16 f16x8;
typedef __attribute__((ext_vector_type(4))) _Float16 f16x4;
typedef __attribute__((ext_vector_type(4))) float f32x4;

typedef __attribute__((address_space(1))) void gvoid_t;
typedef __attribute__((address_space(3))) void lvoid_t;

// async global->LDS, 16B per lane. LDS dest wave-uniform base; HW adds lane*16.
__device__ __forceinline__ void async_copy16(void* lds, const void* g) {
  __builtin_amdgcn_global_load_lds((gvoid_t*)(uintptr_t)g, (lvoid_t*)lds, 16, 0, 0);
}

#define BARRIER()   __builtin_amdgcn_s_barrier()
#define SCHEDBAR()  __builtin_amdgcn_sched_barrier(0)
#define LGKM0()     do { asm volatile("s_waitcnt lgkmcnt(0)" ::: "memory"); SCHEDBAR(); } while (0)
#define VMCNT(n)    do { SCHEDBAR(); asm volatile("s_waitcnt vmcnt(" #n ")"); SCHEDBAR(); } while (0)

#define MFMA16(a, b, c) __builtin_amdgcn_mfma_f32_16x16x32_f16((a), (b), (c), 0, 0, 0)

// 256x256 tile, BK=64, 8 waves (2M x 4N), 8-phase schedule with ONE barrier per
// phase: {reads; stage; [vmcnt]; barrier; lgkm0; cluster}.  Correctness ledger:
//   restage rule: stage at phase p is safe iff p >= q+2 where q = last read-issue
//   phase of that buffer (one full barrier interval between read-complete and
//   stage-issue).  Stage slots: ph0 BH1b(B,2J+1) ph1 AH1a(A,2J+1) ph2 AH1b
//   ph3 BH0a(B,2J+2) ph4 BH0b ph5 AH0a(A,2J+2) ph6 AH0b ph7 BH1a(B,2J+3).
//   Reads: q(BH0)=0, q(AH0)=3, q(BH1)=4, q(AH1)=7 -> all p-q >= 2.  Waits:
//   W1 pre-barrier(3) vmcnt(2) covers AH1+BH1 (read ph4); W2 pre-barrier(7)
//   vmcnt(2) covers BH0+AH0 (read next ph0).  2 instrs staged per phase.
template<int OUT_F16>
__global__ __launch_bounds__(512, 2)
void gemm256(const f16* __restrict__ A, int lda, long sA,
             const f16* __restrict__ B, int ldb, long sB,
             void* __restrict__ Cv, int ldc, long sC,
             const float* __restrict__ bias, float scale, int K)
{
  __shared__ f16 AH0a[8192]; __shared__ f16 AH0b[8192];
  __shared__ f16 AH1a[8192]; __shared__ f16 AH1b[8192];
  __shared__ f16 BH0a[8192]; __shared__ f16 BH0b[8192];
  __shared__ f16 BH1a[8192]; __shared__ f16 BH1b[8192];

  const int tid = threadIdx.x, lane = tid & 63, wave = tid >> 6;
  const int wr = wave >> 2, wc = wave & 3;       // wave -> (M half, N quarter)
  const int l15 = lane & 15, lk = lane >> 4;

  // XCD-aware bijective swizzle of the flattened x-y grid (z untouched)
  int lin = blockIdx.y * gridDim.x + blockIdx.x;
  const int nxy = gridDim.x * gridDim.y;
  if ((nxy & 7) == 0) lin = (lin & 7) * (nxy >> 3) + (lin >> 3);
  const int bx = lin % gridDim.x, by = lin / gridDim.x;

  const long brow = (long)by * 256, bcol = (long)bx * 256;
  const int z = blockIdx.z;
  const f16* Ab = A + (long)z * sA;
  const f16* Bb = B + (long)z * sB;

  // staging: slot=tid covers (row=tid>>3 [+64 for 2nd instr], col8=tid&7) of a
  // 128x64 half; global col-block pre-swizzled gc8 = (tid&7)^(row&7) so the
  // ds_read side applies the same XOR (both-sides-or-neither).
  const int r0  = tid >> 3;                  // 0..63
  const int gc8 = (tid & 7) ^ (r0 & 7);      // (r0+64)&7 == r0&7
  const int sdst = wave * 512;               // wave-uniform elem offset

  const f16* gAa = Ab + (brow + r0) * (long)lda + gc8 * 8;
  const f16* gAb = gAa + 128L * lda;
  const f16* gBa = Bb + (bcol + r0) * (long)ldb + gc8 * 8;
  const f16* gBb = gBa + 128L * ldb;

#define STG(BUF, G, LD, KOFF) { \
    async_copy16(BUF + sdst,        (G) + (KOFF)); \
    async_copy16(BUF + 4096 + sdst, (G) + 64L * (LD) + (KOFF)); }

  // per-wave source halves
  const f16* myA0 = wr ? AH0b : AH0a;
  const f16* myA1 = wr ? AH1b : AH1a;
  const f16* myB0 = (wc & 2) ? BH0b : BH0a;
  const f16* myB1 = (wc & 2) ? BH1b : BH1a;

  // frag read addressing: lr = m16 + l15 (m16 mult of 16 => lr&7 == l15&7)
  const int x8   = l15 & 7;
  const int cb0  = (lk ^ x8) * 8;            // kk=0 col bytes/2
  const int cb1  = ((4 | lk) ^ x8) * 8;      // kk=1
  const int lbA  = l15 * 64;
  const int lbB  = ((wc & 1) * 64 + l15) * 64;

#define RDA4(SRC, MP) { \
    af[0] = *(const f16x8*)&(SRC)[lbA + (2*(MP))   * 1024 + cb0]; \
    af[1] = *(const f16x8*)&(SRC)[lbA + (2*(MP))   * 1024 + cb1]; \
    af[2] = *(const f16x8*)&(SRC)[lbA + (2*(MP)+1) * 1024 + cb0]; \
    af[3] = *(const f16x8*)&(SRC)[lbA + (2*(MP)+1) * 1024 + cb1]; }

#define RDB8(SRC) { \
    bf[0][0] = *(const f16x8*)&(SRC)[lbB + 0 * 1024 + cb0]; \
    bf[1][0] = *(const f16x8*)&(SRC)[lbB + 0 * 1024 + cb1]; \
    bf[0][1] = *(const f16x8*)&(SRC)[lbB + 1 * 1024 + cb0]; \
    bf[1][1] = *(const f16x8*)&(SRC)[lbB + 1 * 1024 + cb1]; \
    bf[0][2] = *(const f16x8*)&(SRC)[lbB + 2 * 1024 + cb0]; \
    bf[1][2] = *(const f16x8*)&(SRC)[lbB + 2 * 1024 + cb1]; \
    bf[0][3] = *(const f16x8*)&(SRC)[lbB + 3 * 1024 + cb0]; \
    bf[1][3] = *(const f16x8*)&(SRC)[lbB + 3 * 1024 + cb1]; }

#define CLUSTER(MP) { \
    __builtin_amdgcn_s_setprio(1); \
    _Pragma("unroll") \
    for (int n = 0; n < 4; ++n) { \
      f32x4 t = MFMA16(af[0], bf[0][n], acc[2*(MP)][n]); \
      acc[2*(MP)][n] = MFMA16(af[1], bf[1][n], t); \
    } \
    _Pragma("unroll") \
    for (int n = 0; n < 4; ++n) { \
      f32x4 t = MFMA16(af[2], bf[0][n], acc[2*(MP)+1][n]); \
      acc[2*(MP)+1][n] = MFMA16(af[3], bf[1][n], t); \
    } \
    __builtin_amdgcn_s_setprio(0); }

  f32x4 acc[8][4] = {};
  f16x8 af[4], bf[2][4];
  const int NIT = K >> 7;                    // K/128

  // prologue: B0, A0, B1-half-a (10 instrs); vmcnt(2) leaves BH1a in flight.
  STG(BH0a, gBa, ldb, 0);  STG(BH0b, gBb, ldb, 0);
  STG(AH0a, gAa, lda, 0);  STG(AH0b, gAb, lda, 0);
  STG(BH1a, gBa, ldb, 64);
  VMCNT(2);
  BARRIER();

  for (int J = 0; J < NIT; ++J) {
    const long k1 = 128L * J + 64;           // tile 2J+1
    const long k2 = 128L * J + 128;          // tile 2J+2
    const long k3 = 128L * J + 192;          // tile 2J+3
    const bool st = (J + 1 < NIT);

    // ---- K-tile T=2J (buf0): phases 0-3 ----
    RDA4(myA0, 0); RDB8(myB0);
    STG(BH1b, gBb, ldb, k1);                 // completes BH1 pair (read ph4)
    BARRIER(); LGKM0(); CLUSTER(0);

    RDA4(myA0, 1);
    STG(AH1a, gAa, lda, k1);
    BARRIER(); LGKM0(); CLUSTER(1);

    RDA4(myA0, 2);
    STG(AH1b, gAb, lda, k1);
    BARRIER(); LGKM0(); CLUSTER(2);

    RDA4(myA0, 3);
    if (st) { STG(BH0a, gBa, ldb, k2); VMCNT(2); } else { VMCNT(0); }  // W1
    BARRIER(); LGKM0(); CLUSTER(3);

    // ---- K-tile T+1 (buf1): phases 4-7 ----
    RDA4(myA1, 0); RDB8(myB1);
    if (st) STG(BH0b, gBb, ldb, k2);
    BARRIER(); LGKM0(); CLUSTER(0);

    RDA4(myA1, 1);
    if (st) STG(AH0a, gAa, lda, k2);
    BARRIER(); LGKM0(); CLUSTER(1);

    RDA4(myA1, 2);
    if (st) STG(AH0b, gAb, lda, k2);
    BARRIER(); LGKM0(); CLUSTER(2);

    RDA4(myA1, 3);
    if (st) { STG(BH1a, gBa, ldb, k3); VMCNT(2); }                     // W2
    BARRIER(); LGKM0(); CLUSTER(3);
  }

  // epilogue: C/D layout col = lane&15, row = (lane>>4)*4 + j
#pragma unroll
  for (int m = 0; m < 8; ++m) {
#pragma unroll
    for (int n = 0; n < 4; ++n) {
      const long col = bcol + wc * 64 + n * 16 + l15;
      const float bv = bias ? bias[col] : 0.0f;
#pragma unroll
      for (int j = 0; j < 4; ++j) {
        const long row = brow + wr * 128 + m * 16 + lk * 4 + j;
        const float v = acc[m][n][j] * scale + bv;
        if (OUT_F16)
          ((f16*)Cv)[(long)z * sC + row * ldc + col] = (f16)v;
        else
          ((float*)Cv)[(long)z * sC + row * ldc + col] = v;
      }
    }
  }
#undef STG
#undef RDA4
#undef RDB8
#undef CLUSTER
}

__global__ void cast_f32_f16(const float* __restrict__ in, f16* __restrict__ out, long n) {
  long i = ((long)blockIdx.x * blockDim.x + threadIdx.x) * 4;
  const long stride = (long)gridDim.x * blockDim.x * 4;
  for (; i < n; i += stride) {
    const float4 v = *reinterpret_cast<const float4*>(in + i);
    f16x4 h;
    h.x = (f16)v.x; h.y = (f16)v.y; h.z = (f16)v.z; h.w = (f16)v.w;
    *reinterpret_cast<f16x4*>(out + i) = h;
  }
}

// vt[b][h][s] = qkv[b*2048+s][4096+h]   (extract V and transpose, per batch)
__global__ __launch_bounds__(256)
void transpose_v(const f16* __restrict__ qkv, f16* __restrict__ vt) {
  __shared__ f16 t[32][33];
  const int b = blockIdx.z;
  const int s0 = blockIdx.y * 32, h0 = blockIdx.x * 32;
  const int tx = threadIdx.x, ty = threadIdx.y;  // 32 x 8
  const f16* src = qkv + (long)b * 2048 * 6144 + 4096;
  f16* dst = vt + (long)b * 2048 * 2048;
#pragma unroll
  for (int i = 0; i < 4; ++i)
    t[ty + i * 8][tx] = src[(long)(s0 + ty + i * 8) * 6144 + h0 + tx];
  __syncthreads();
#pragma unroll
  for (int i = 0; i < 4; ++i)
    dst[(long)(h0 + ty + i * 8) * 2048 + s0 + tx] = t[tx][ty + i * 8];
}

// one block per row of 2048 f32 scores; writes f16 probs in-place (row stride 4096 f16)
__global__ __launch_bounds__(256)
void softmax_rows(float* __restrict__ scores) {
  const long row = blockIdx.x;
  float* s = scores + row * 2048;
  const int tid = threadIdx.x;
  const int lane = tid & 63;
  const int wave = tid >> 6;

  const float4 a = *reinterpret_cast<const float4*>(s + tid * 8);
  const float4 b = *reinterpret_cast<const float4*>(s + tid * 8 + 4);
  float v[8] = {a.x, a.y, a.z, a.w, b.x, b.y, b.z, b.w};

  float mx = v[0];
#pragma unroll
  for (int j = 1; j < 8; ++j) mx = fmaxf(mx, v[j]);
#pragma unroll
  for (int off = 32; off >= 1; off >>= 1) mx = fmaxf(mx, __shfl_xor(mx, off));
  __shared__ float red[4];
  if (lane == 0) red[wave] = mx;
  __syncthreads();
  mx = fmaxf(fmaxf(red[0], red[1]), fmaxf(red[2], red[3]));

  float sum = 0.f;
#pragma unroll
  for (int j = 0; j < 8; ++j) { v[j] = __expf(v[j] - mx); sum += v[j]; }
#pragma unroll
  for (int off = 32; off >= 1; off >>= 1) sum += __shfl_xor(sum, off);
  __shared__ float red2[4];
  if (lane == 0) red2[wave] = sum;
  __syncthreads();
  const float inv = 1.0f / (red2[0] + red2[1] + red2[2] + red2[3]);

  f16* p = reinterpret_cast<f16*>(scores) + row * 4096 + tid * 8;
  f16x8 h;
#pragma unroll
  for (int j = 0; j < 8; ++j) h[j] = (f16)(v[j] * inv);
  *reinterpret_cast<f16x8*>(p) = h;
}

extern "C" void kernel_launch(void* const* d_in, const int* in_sizes, int n_in,
                              void* d_out, int out_size, void* d_ws, size_t ws_size,
                              hipStream_t stream) {
  const float* x     = (const float*)d_in[0];  // [4,2048,2048]
  const float* w_qkv = (const float*)d_in[1];  // [6144,2048]
  const float* b_qkv = (const float*)d_in[2];  // [6144]
  const float* w_out = (const float*)d_in[3];  // [2048,2048]
  const float* b_out = (const float*)d_in[4];  // [2048]
  float* out = (float*)d_out;                  // [4,2048,2048] f32

  char* ws = (char*)d_ws;
  f16*   Xh    = (f16*)(ws + 0);           //  33.5 MB  [8192][2048]
  f16*   Wqkvh = (f16*)(ws + 33554432L);   //  25.2 MB  [6144][2048]
  f16*   Wouth = (f16*)(ws + 58720256L);   //   8.4 MB  [2048][2048]
  f16*   QKV   = (f16*)(ws + 67108864L);   // 100.7 MB  [8192][6144]
  float* SC    = (float*)(ws + 167772160L);//  67.1 MB  [4][2048][2048] f32 (probs f16 in-place)
  f16*   VT    = (f16*)(ws + 234881024L);  //  33.5 MB  [4][2048][2048]
  f16*   CTX   = Xh;                       // reuse X region after gemm1

  const float inv_sqrt_h = 0.022097086912079608f;  // 1/sqrt(2048)

  cast_f32_f16<<<2048, 256, 0, stream>>>(x,     Xh,    16777216L);
  cast_f32_f16<<<2048, 256, 0, stream>>>(w_qkv, Wqkvh, 12582912L);
  cast_f32_f16<<<1024, 256, 0, stream>>>(w_out, Wouth, 4194304L);

  // qkv = x @ w_qkv^T + b_qkv   [8192 x 6144]
  gemm256<1><<<dim3(24, 32, 1), 512, 0, stream>>>(
      Xh, 2048, 0, Wqkvh, 2048, 0, QKV, 6144, 0, b_qkv, 1.0f, 2048);

  // scores = Q @ K^T / sqrt(H)  per batch  [2048 x 2048] f32
  gemm256<0><<<dim3(8, 8, 4), 512, 0, stream>>>(
      QKV, 6144, 2048L * 6144, QKV + 2048, 6144, 2048L * 6144,
      SC, 2048, 2048L * 2048, nullptr, inv_sqrt_h, 2048);

  transpose_v<<<dim3(64, 64, 4), dim3(32, 8), 0, stream>>>(QKV, VT);

  softmax_rows<<<8192, 256, 0, stream>>>(SC);

  // context = P @ V  per batch (probs f16 in-place in SC, row stride 4096)
  gemm256<1><<<dim3(8, 8, 4), 512, 0, stream>>>(
      (const f16*)SC, 4096, 2048L * 4096, VT, 2048, 2048L * 2048,
      CTX, 2048, 2048L * 2048, nullptr, 1.0f, 2048);

  // out = context @ w_out^T + b_out   [8192 x 2048] f32
  gemm256<0><<<dim3(8, 32, 1), 512, 0, stream>>>(
      CTX, 2048, 0, Wouth, 2048, 0, out, 2048, 0, b_out, 1.0f, 2048);
}